// Round 2
// baseline (229.045 us; speedup 1.0000x reference)
//
#include <hip/hip_runtime.h>

#define T_DIM 60
#define NBLK 3840                 // NT / 256 (983040), elements per block = 256

typedef float v4f __attribute__((ext_vector_type(4)));
typedef float v2f __attribute__((ext_vector_type(2)));

// Fused single-pass kernel. Block handles 256 CONSECUTIVE elements (n*T+t).
// v3 changes vs v2 (228 µs):
//  - ALL 16 bulk loads (8x sigma dwordx4 + 8x mu dwordx2) issued into
//    registers at kernel top, BEFORE the LDS staging + syncthreads ->
//    max outstanding loads per wave (12 KB in flight).
//  - loop body is a single basic block: the divergent (l==0) atomic
//    region is deferred to one epilogue. v2 had an exec-mask region per
//    unrolled iteration, which blocked cross-iteration load hoisting and
//    capped streaming at ~2.8 TB/s (latency-convoy, not BW).
//  - exp chain shortened: exp(pv - 0.5*maha) * rsq(det) — rsq runs
//    parallel to the maha chain instead of log(det) serializing into exp.
//  - __launch_bounds__(256,4): cap 128 VGPRs -> 16 waves/CU.
__global__ __launch_bounds__(256, 4)
void loss_fused_kernel(const float* __restrict__ mu,
                       const float* __restrict__ sigma,
                       const float* __restrict__ pi,
                       const float* __restrict__ x,
                       const float* __restrict__ mask,
                       float* __restrict__ loss_p,
                       float* __restrict__ mask_p,
                       float* __restrict__ out) {
    __shared__ float bl[T_DIM], bm[T_DIM];
    __shared__ float s_lsepi[8];
    __shared__ float s_piv[48];       // <=6 pi rows, value - LOG_2PI
    __shared__ v2f   s_x[256];
    __shared__ float s_mk[256];
    const float LOG_2PI = 1.8378770664093453f;
    int tid = threadIdx.x;
    int E0 = blockIdx.x * 256;
    int n_base = E0 / T_DIM;
    int ncnt = (E0 + 255) / T_DIM - n_base + 1;   // <= 6

    int l = tid & 7;                  // owned mixture component
    int oct = tid >> 3;               // 0..31
    size_t e0 = (size_t)E0 + oct;

    // ---- Phase 1: issue the 16 bulk loads (independent of LDS) ----
    v4f sg[8]; v2f m2[8];
#pragma unroll
    for (int it = 0; it < 8; ++it) {
        sg[it] = __builtin_nontemporal_load((const v4f*)sigma + (e0 + 32 * it) * 8 + l);
        m2[it] = __builtin_nontemporal_load((const v2f*)mu + (e0 + 32 * it) * 8 + l);
    }

    // ---- Phase 2: staging (overlaps with the in-flight bulk loads) ----
    if (tid < T_DIM) { bl[tid] = 0.0f; bm[tid] = 0.0f; }
    s_x[tid]  = __builtin_nontemporal_load((const v2f*)x + E0 + tid);
    s_mk[tid] = __builtin_nontemporal_load(mask + E0 + tid);
    if (tid < 8 * ncnt)
        s_piv[tid] = pi[(size_t)n_base * 8 + tid] - LOG_2PI;
    if (blockIdx.x == 0 && tid == 0) out[0] = 0.0f;
    __syncthreads();
    if (tid < ncnt) {
        const float* pr = s_piv + tid * 8;
        float q0 = pr[0], q1 = pr[1], q2 = pr[2], q3 = pr[3];
        float q4 = pr[4], q5 = pr[5], q6 = pr[6], q7 = pr[7];
        float mx = fmaxf(fmaxf(fmaxf(q0, q1), fmaxf(q2, q3)),
                         fmaxf(fmaxf(q4, q5), fmaxf(q6, q7)));
        float s = __expf(q0 - mx) + __expf(q1 - mx) + __expf(q2 - mx) +
                  __expf(q3 - mx) + __expf(q4 - mx) + __expf(q5 - mx) +
                  __expf(q6 - mx) + __expf(q7 - mx);
        s_lsepi[tid] = mx + __logf(s) + LOG_2PI;   // lse of RAW pi row
    }
    __syncthreads();

    // ---- Phase 3: compute loop — single basic block, no divergence ----
    int idx = oct;                    // element - E0 (LDS index), += 32 per it
    int n0 = (E0 + oct) / T_DIM;
    int t = (E0 + oct) - n0 * T_DIM;
    int nb = n0 - n_base;
    const int t_init = t;
    float vout[8], mks[8];

#pragma unroll
    for (int it = 0; it < 8; ++it) {
        v2f xv = s_x[idx];            // broadcast within octet, conflict-free
        float mk = s_mk[idx];
        float pv = s_piv[nb * 8 + l]; // pi - LOG_2PI

        // closed-form 2x2: det = ac-b^2, maha = (c d1^2 - 2b d1 d2 + a d2^2)/det
        float a = sg[it].x, b = sg[it].y, c = sg[it].w;
        float d1 = xv.x - m2[it].x, d2 = xv.y - m2[it].y;
        float det = a * c - b * b;                     // >= 0.25 (SPD + 0.5I)
        float rdet = __builtin_amdgcn_rcpf(det);
        float maha = (c * d1 * d1 - 2.0f * b * d1 * d2 + a * d2 * d2) * rdet;
        // component density term: exp(pv - 0.5*maha) / sqrt(det)
        float g = __expf(__builtin_fmaf(-0.5f, maha, pv)) *
                  __builtin_amdgcn_rsqf(det);

        // sum over the 8 components (all values positive, bounded ~1e2)
        float s = g;
        s += __shfl_xor(s, 1);
        s += __shfl_xor(s, 2);
        s += __shfl_xor(s, 4);

        // all lanes compute (octet-uniform) — keeps the loop branch-free
        vout[it] = (s_lsepi[nb] - __logf(s)) * mk;     // -gmm_lp * mask
        mks[it]  = mk;

        idx += 32;
        t += 32;
        if (t >= T_DIM) { t -= T_DIM; nb += 1; }       // cndmask, no branch
    }

    // ---- Phase 4: single divergent epilogue — all atomics at once ----
    if (l == 0) {
        int t2 = t_init;
#pragma unroll
        for (int it = 0; it < 8; ++it) {
            atomicAdd(&bl[t2], vout[it]);
            atomicAdd(&bm[t2], mks[it]);
            t2 += 32;
            if (t2 >= T_DIM) t2 -= T_DIM;
        }
    }
    __syncthreads();
    if (tid < T_DIM) {
        loss_p[(size_t)tid * NBLK + blockIdx.x] = bl[tid];
        mask_p[(size_t)tid * NBLK + blockIdx.x] = bm[tid];
    }
}

// 60 blocks: block t sums its coalesced partial row, atomically accumulates
// t_loss/npred into out[0] (zeroed by loss_fused_kernel, stream-ordered).
__global__ void reduce_t_kernel(const float* __restrict__ loss_p,
                                const float* __restrict__ mask_p,
                                float* __restrict__ out, int nblocks) {
    int t = blockIdx.x;
    const float* lrow = loss_p + (size_t)t * nblocks;
    const float* mrow = mask_p + (size_t)t * nblocks;
    float sl = 0.0f, sm = 0.0f;
    for (int i = threadIdx.x; i < nblocks; i += blockDim.x) {
        sl += lrow[i]; sm += mrow[i];
    }
#pragma unroll
    for (int off = 32; off > 0; off >>= 1) {
        sl += __shfl_down(sl, off); sm += __shfl_down(sm, off);
    }
    __shared__ float wl[4], wm[4];
    int lane = threadIdx.x & 63, w = threadIdx.x >> 6;
    if (lane == 0) { wl[w] = sl; wm[w] = sm; }
    __syncthreads();
    if (threadIdx.x == 0)
        atomicAdd(out, (wl[0] + wl[1] + wl[2] + wl[3]) /
                       (wm[0] + wm[1] + wm[2] + wm[3]));
}

extern "C" void kernel_launch(void* const* d_in, const int* in_sizes, int n_in,
                              void* d_out, int out_size, void* d_ws, size_t ws_size,
                              hipStream_t stream) {
    const float* mu    = (const float*)d_in[0];   // (N,T,M,K)
    const float* sigma = (const float*)d_in[1];   // (N,T,M,K,K)
    const float* pi    = (const float*)d_in[2];   // (N,M)
    const float* x     = (const float*)d_in[3];   // (N,T,K)
    const float* mask  = (const float*)d_in[4];   // (N,T)
    float* out = (float*)d_out;
    float* ws = (float*)d_ws;
    // ws layout (1.8 MB of ~480 MB): loss_p | mask_p
    float* loss_p = ws;
    float* mask_p = ws + (size_t)T_DIM * NBLK;

    hipLaunchKernelGGL(loss_fused_kernel, dim3(NBLK), dim3(256), 0, stream,
                       mu, sigma, pi, x, mask, loss_p, mask_p, out);
    hipLaunchKernelGGL(reduce_t_kernel, dim3(T_DIM), dim3(256), 0, stream,
                       loss_p, mask_p, out, NBLK);
}

// Round 3
// 227.629 us; speedup vs baseline: 1.0062x; 1.0062x over previous
//
#include <hip/hip_runtime.h>

#define T_DIM 60
#define NBLK 3840                 // NT / 256 (983040), elements per block = 256

typedef float v4f __attribute__((ext_vector_type(4)));
typedef float v2f __attribute__((ext_vector_type(2)));

// Fused single-pass kernel. Block handles 256 CONSECUTIVE elements (n*T+t).
// v4 changes vs v3 (229 µs, neutral):
//  - PHASE ORDER INVERTED: staging + the single __syncthreads() now come
//    BEFORE the 16 bulk loads. v3 issued loads, then hit the barrier's
//    mandatory s_waitcnt vmcnt(0) drain -> every wave stalled until ALL
//    loads returned, then computed with its memory pipe idle (read duty
//    cycle ~0.45 -> the observed 2.9 TB/s plateau). Now there is NO
//    barrier between load issue and compute: the compiler emits counted
//    per-use waits (vmcnt(14), vmcnt(12), ...), so iteration 0 computes
//    while iterations 1..7 are still in flight and returns flow
//    continuously through the whole block lifetime.
//  - one barrier instead of two: lsepi is computed from a redundant
//    direct global read of the pi row (L2-hot) instead of from s_piv.
//  - loop body stays branch-free (atomics deferred to epilogue, v3).
__global__ __launch_bounds__(256, 4)
void loss_fused_kernel(const float* __restrict__ mu,
                       const float* __restrict__ sigma,
                       const float* __restrict__ pi,
                       const float* __restrict__ x,
                       const float* __restrict__ mask,
                       float* __restrict__ loss_p,
                       float* __restrict__ mask_p,
                       float* __restrict__ out) {
    __shared__ float bl[T_DIM], bm[T_DIM];
    __shared__ float s_lsepi[8];
    __shared__ float s_piv[48];       // <=6 pi rows, value - LOG_2PI
    __shared__ v2f   s_x[256];
    __shared__ float s_mk[256];
    const float LOG_2PI = 1.8378770664093453f;
    int tid = threadIdx.x;
    int E0 = blockIdx.x * 256;
    int n_base = E0 / T_DIM;
    int ncnt = (E0 + 255) / T_DIM - n_base + 1;   // <= 6

    // ---- Phase 1: staging (small loads) + ONE barrier ----
    if (tid < T_DIM) { bl[tid] = 0.0f; bm[tid] = 0.0f; }
    s_x[tid]  = __builtin_nontemporal_load((const v2f*)x + E0 + tid);
    s_mk[tid] = __builtin_nontemporal_load(mask + E0 + tid);
    if (tid < 8 * ncnt)
        s_piv[tid] = pi[(size_t)n_base * 8 + tid] - LOG_2PI;
    if (tid < ncnt) {
        // redundant direct read of the pi row (8 floats, L2-hot) so the
        // LSE needs no intermediate barrier on s_piv
        const float* pr = pi + (size_t)(n_base + tid) * 8;
        float q0 = pr[0], q1 = pr[1], q2 = pr[2], q3 = pr[3];
        float q4 = pr[4], q5 = pr[5], q6 = pr[6], q7 = pr[7];
        float mx = fmaxf(fmaxf(fmaxf(q0, q1), fmaxf(q2, q3)),
                         fmaxf(fmaxf(q4, q5), fmaxf(q6, q7)));
        float s = __expf(q0 - mx) + __expf(q1 - mx) + __expf(q2 - mx) +
                  __expf(q3 - mx) + __expf(q4 - mx) + __expf(q5 - mx) +
                  __expf(q6 - mx) + __expf(q7 - mx);
        s_lsepi[tid] = mx + __logf(s);           // lse of RAW pi row
    }
    if (blockIdx.x == 0 && tid == 0) out[0] = 0.0f;
    __syncthreads();

    // ---- Phase 2: issue all 16 bulk loads (NO barrier after this) ----
    int l = tid & 7;                  // owned mixture component
    int oct = tid >> 3;               // 0..31
    size_t e0 = (size_t)E0 + oct;
    v4f sg[8]; v2f m2[8];
#pragma unroll
    for (int it = 0; it < 8; ++it) {
        sg[it] = __builtin_nontemporal_load((const v4f*)sigma + (e0 + 32 * it) * 8 + l);
        m2[it] = __builtin_nontemporal_load((const v2f*)mu + (e0 + 32 * it) * 8 + l);
    }

    // ---- Phase 3: compute loop — counted vmcnt waits, overlaps returns ----
    int idx = oct;                    // element - E0 (LDS index), += 32 per it
    int n0 = (E0 + oct) / T_DIM;
    int t = (E0 + oct) - n0 * T_DIM;
    int nb = n0 - n_base;
    const int t_init = t;
    float vout[8], mks[8];

#pragma unroll
    for (int it = 0; it < 8; ++it) {
        v2f xv = s_x[idx];            // broadcast within octet, conflict-free
        float mk = s_mk[idx];
        float pv = s_piv[nb * 8 + l]; // pi - LOG_2PI

        // closed-form 2x2: det = ac-b^2, maha = (c d1^2 - 2b d1 d2 + a d2^2)/det
        float a = sg[it].x, b = sg[it].y, c = sg[it].w;
        float d1 = xv.x - m2[it].x, d2 = xv.y - m2[it].y;
        float det = a * c - b * b;                     // >= 0.25 (SPD + 0.5I)
        float rdet = __builtin_amdgcn_rcpf(det);
        float maha = (c * d1 * d1 - 2.0f * b * d1 * d2 + a * d2 * d2) * rdet;
        // component density term: exp(pv - 0.5*maha) / sqrt(det)
        float g = __expf(__builtin_fmaf(-0.5f, maha, pv)) *
                  __builtin_amdgcn_rsqf(det);

        // sum over the 8 components (all values positive, bounded ~1e2)
        float s = g;
        s += __shfl_xor(s, 1);
        s += __shfl_xor(s, 2);
        s += __shfl_xor(s, 4);

        // all lanes compute (octet-uniform) — keeps the loop branch-free
        vout[it] = (s_lsepi[nb] - __logf(s)) * mk;     // -gmm_lp * mask
        mks[it]  = mk;

        idx += 32;
        t += 32;
        if (t >= T_DIM) { t -= T_DIM; nb += 1; }       // cndmask, no branch
    }

    // ---- Phase 4: single divergent epilogue — all atomics at once ----
    if (l == 0) {
        int t2 = t_init;
#pragma unroll
        for (int it = 0; it < 8; ++it) {
            atomicAdd(&bl[t2], vout[it]);
            atomicAdd(&bm[t2], mks[it]);
            t2 += 32;
            if (t2 >= T_DIM) t2 -= T_DIM;
        }
    }
    __syncthreads();
    if (tid < T_DIM) {
        loss_p[(size_t)tid * NBLK + blockIdx.x] = bl[tid];
        mask_p[(size_t)tid * NBLK + blockIdx.x] = bm[tid];
    }
}

// 60 blocks: block t sums its coalesced partial row, atomically accumulates
// t_loss/npred into out[0] (zeroed by loss_fused_kernel, stream-ordered).
__global__ void reduce_t_kernel(const float* __restrict__ loss_p,
                                const float* __restrict__ mask_p,
                                float* __restrict__ out, int nblocks) {
    int t = blockIdx.x;
    const float* lrow = loss_p + (size_t)t * nblocks;
    const float* mrow = mask_p + (size_t)t * nblocks;
    float sl = 0.0f, sm = 0.0f;
    for (int i = threadIdx.x; i < nblocks; i += blockDim.x) {
        sl += lrow[i]; sm += mrow[i];
    }
#pragma unroll
    for (int off = 32; off > 0; off >>= 1) {
        sl += __shfl_down(sl, off); sm += __shfl_down(sm, off);
    }
    __shared__ float wl[4], wm[4];
    int lane = threadIdx.x & 63, w = threadIdx.x >> 6;
    if (lane == 0) { wl[w] = sl; wm[w] = sm; }
    __syncthreads();
    if (threadIdx.x == 0)
        atomicAdd(out, (wl[0] + wl[1] + wl[2] + wl[3]) /
                       (wm[0] + wm[1] + wm[2] + wm[3]));
}

extern "C" void kernel_launch(void* const* d_in, const int* in_sizes, int n_in,
                              void* d_out, int out_size, void* d_ws, size_t ws_size,
                              hipStream_t stream) {
    const float* mu    = (const float*)d_in[0];   // (N,T,M,K)
    const float* sigma = (const float*)d_in[1];   // (N,T,M,K,K)
    const float* pi    = (const float*)d_in[2];   // (N,M)
    const float* x     = (const float*)d_in[3];   // (N,T,K)
    const float* mask  = (const float*)d_in[4];   // (N,T)
    float* out = (float*)d_out;
    float* ws = (float*)d_ws;
    // ws layout (1.8 MB of ~480 MB): loss_p | mask_p
    float* loss_p = ws;
    float* mask_p = ws + (size_t)T_DIM * NBLK;

    hipLaunchKernelGGL(loss_fused_kernel, dim3(NBLK), dim3(256), 0, stream,
                       mu, sigma, pi, x, mask, loss_p, mask_p, out);
    hipLaunchKernelGGL(reduce_t_kernel, dim3(T_DIM), dim3(256), 0, stream,
                       loss_p, mask_p, out, NBLK);
}